// Round 1
// baseline (1057.151 us; speedup 1.0000x reference)
//
#include <hip/hip_runtime.h>
#include <math.h>

#define IGNORE_LABEL 255
#define NCLS 200
#define NDOM 3
#define NBLOCKS 2048
#define NTHREADS 256
#define WAVES_PER_BLOCK (NTHREADS / 64)

// Stage 1: each wave handles one row per grid-stride iteration.
// Row = 200 f32 = 50 float4 -> lanes 0..49 load one float4 each (coalesced 800B).
__global__ __launch_bounds__(NTHREADS) void dcl_partial(
    const float* __restrict__ x,     // [N, 200]
    const int*   __restrict__ tgt,   // [N]
    const int*   __restrict__ dom,   // [N]
    const float* __restrict__ cnt,   // [3, 200]
    double*      __restrict__ psum,  // [NBLOCKS]
    int*         __restrict__ pcnt,  // [NBLOCKS]
    int N)
{
    __shared__ __align__(16) float lc[NDOM][NCLS];   // log(domain_counts), 2.4 KB
    const int tid = threadIdx.x;
    for (int i = tid; i < NDOM * NCLS; i += NTHREADS)
        (&lc[0][0])[i] = logf(cnt[i]);
    __syncthreads();

    const int lane = tid & 63;
    const int wave = tid >> 6;
    const int wid  = blockIdx.x * WAVES_PER_BLOCK + wave;
    const int nw   = NBLOCKS * WAVES_PER_BLOCK;

    double lsum = 0.0;
    int    lcnt = 0;

    for (int row = wid; row < N; row += nw) {
        const float4* xr = reinterpret_cast<const float4*>(x + (size_t)row * NCLS);
        const int d = dom[row];
        const int t = tgt[row];

        float z0 = 0.f, z1 = 0.f, z2 = 0.f, z3 = 0.f;
        float m = -INFINITY;
        if (lane < NCLS / 4) {
            float4 xv = xr[lane];
            const float4* lcr = reinterpret_cast<const float4*>(&lc[d][0]);
            float4 lv = lcr[lane];
            z0 = xv.x + lv.x; z1 = xv.y + lv.y;
            z2 = xv.z + lv.z; z3 = xv.w + lv.w;
            m = fmaxf(fmaxf(z0, z1), fmaxf(z2, z3));
        }
        #pragma unroll
        for (int off = 32; off; off >>= 1)
            m = fmaxf(m, __shfl_xor(m, off));

        float se = 0.f, zt = 0.f;
        if (lane < NCLS / 4) {
            se = __expf(z0 - m) + __expf(z1 - m) + __expf(z2 - m) + __expf(z3 - m);
            const int r = t - lane * 4;
            if ((unsigned)r < 4u)
                zt = (r == 0) ? z0 : (r == 1) ? z1 : (r == 2) ? z2 : z3;
        }
        #pragma unroll
        for (int off = 32; off; off >>= 1) {
            se += __shfl_xor(se, off);
            zt += __shfl_xor(zt, off);
        }

        if (t != IGNORE_LABEL) {
            lsum += (double)((m + logf(se)) - zt);   // all lanes identical; lane 0 used
            lcnt += 1;
        }
    }

    __shared__ double sd[WAVES_PER_BLOCK];
    __shared__ int    sc[WAVES_PER_BLOCK];
    if (lane == 0) { sd[wave] = lsum; sc[wave] = lcnt; }
    __syncthreads();
    if (tid == 0) {
        double S = 0.0; int C = 0;
        #pragma unroll
        for (int w = 0; w < WAVES_PER_BLOCK; ++w) { S += sd[w]; C += sc[w]; }
        psum[blockIdx.x] = S;   // every block writes its slot every launch
        pcnt[blockIdx.x] = C;
    }
}

// Stage 2: single block reduces the 2048 partials and writes the scalar loss.
__global__ __launch_bounds__(256) void dcl_final(
    const double* __restrict__ psum,
    const int*    __restrict__ pcnt,
    float*        __restrict__ out)
{
    const int tid = threadIdx.x;
    double s = 0.0; int c = 0;
    for (int i = tid; i < NBLOCKS; i += 256) { s += psum[i]; c += pcnt[i]; }
    #pragma unroll
    for (int off = 32; off; off >>= 1) {
        s += __shfl_xor(s, off);
        c += __shfl_xor(c, off);
    }
    __shared__ double sd[4];
    __shared__ int    sc[4];
    const int lane = tid & 63, wave = tid >> 6;
    if (lane == 0) { sd[wave] = s; sc[wave] = c; }
    __syncthreads();
    if (tid == 0) {
        double S = sd[0] + sd[1] + sd[2] + sd[3];
        int    C = sc[0] + sc[1] + sc[2] + sc[3];
        out[0] = (float)(S / (double)C);
    }
}

extern "C" void kernel_launch(void* const* d_in, const int* in_sizes, int n_in,
                              void* d_out, int out_size, void* d_ws, size_t ws_size,
                              hipStream_t stream) {
    const float* x   = (const float*)d_in[0];   // inputs [N,200] f32
    const int*   tgt = (const int*)  d_in[1];   // targets [N] i32
    const int*   dom = (const int*)  d_in[2];   // domains [N] i32
    const float* cnt = (const float*)d_in[3];   // domain_counts [3,200] f32
    const int N = in_sizes[1];

    double* psum = (double*)d_ws;
    int*    pcnt = (int*)((char*)d_ws + NBLOCKS * sizeof(double));

    dcl_partial<<<NBLOCKS, NTHREADS, 0, stream>>>(x, tgt, dom, cnt, psum, pcnt, N);
    dcl_final<<<1, 256, 0, stream>>>(psum, pcnt, (float*)d_out);
}